// Round 2
// 136.302 us; speedup vs baseline: 1.0160x; 1.0160x over previous
//
#include <hip/hip_runtime.h>
#include <math.h>

// Problem constants (from reference)
#define NDIM   8
#define NBINS  64
#define LOG_BETA   (-13.815510557964274f)  // log(1e-6)
#define LN2F       0.69314718055994531f
// mesh is geometric: boundary_j (original coords) = x1L*(1.2^j-1)/0.2, j=0..32
// bin index from |x|: g = log2(1 + ALPHA*|x|) / log2(1.2);  ALPHA = (1.2^32-1)/10
#define ALPHA      34.0821892f
#define INV_LOG2R  3.80178401692393f       // 1/log2(1.2)
#define L2R        0.26303440583379378f    // log2(1.2)

typedef float f32x4 __attribute__((ext_vector_type(4)));  // clang vector: ok for nontemporal builtins

// Two threads per point: lane g handles float4 half (g&1) of point (g>>1).
// All x loads / y stores are dense 16 B/lane (no stride-32B AoS penalty).
__global__ __launch_bounds__(256, 8) void cdfq_fused(const float* __restrict__ x,
                                                     const float* __restrict__ logdet_in,
                                                     const float* __restrict__ p,
                                                     float* __restrict__ y_out,
                                                     float* __restrict__ ld_out,
                                                     int n)
{
    __shared__ float4 stbl[NDIM * NBINS];  // [d][k]: {v1, slope, F_pre, mesh_k}

    const int t  = threadIdx.x;
    const int T  = gridDim.x * blockDim.x;         // work-item stride
    const int i0 = blockIdx.x * blockDim.x + t;
    const int G  = 2 * n;                          // work items = half-points
    const int iters = G / T;                       // wave-uniform (8 here)
    const float4* xv4 = (const float4*)x;

    // ---- prologue: 2-deep prefetch issued BEFORE prep so the first two
    //      memory latencies hide behind prep's VALU/shuffle work ----
    float4 X0, X1; float L0, L1;
    if (iters > 0) { X0 = xv4[i0];     L0 = logdet_in[i0 >> 1]; }
    if (iters > 1) { X1 = xv4[i0 + T]; L1 = logdet_in[(i0 + T) >> 1]; }
    __builtin_amdgcn_sched_barrier(0);   // do not sink these below prep

    // ---- prep: each wave builds TWO dims of the table fully in-register.
    //      No mesh/elmt/pdfs LDS arrays, no powf, ONE barrier total. ----
    {
        const int lane = t & 63;
        const int w    = t >> 6;
        const float pw32 = exp2f(32.0f * L2R);     // 1.2^32
        const float inv  = 0.5f / (pw32 - 1.0f);
        auto meshf = [&](float tt) {               // normalized mesh coordinate
            float fidx = tt - 32.0f;
            float pw = exp2f(fabsf(fidx) * L2R);
            float r  = (pw - 1.0f) * inv;
            return 0.5f + ((fidx >= 0.0f) ? r : -r);
        };
        const float m0  = meshf((float)lane);          // mesh[lane]
        const float m1  = meshf((float)(lane + 1));    // mesh[lane+1]
        const float el  = m1 - m0;                     // elmt[lane]
        const float el1 = __shfl_down(el, 1);          // elmt[lane+1] (lane63 unused)
        const float e0e63 = 2.0f * (meshf(1.0f) - meshf(0.0f)); // elmt[0]+elmt[63]

#pragma unroll
        for (int dd = 0; dd < 2; ++dd) {
            const int d = 2 * w + dd;
            float ep = 0.0f;
            if (lane < 63) ep = __expf(p[lane * NDIM + d]);  // interior node lane+1
            // normalization: sum of ep * (elmt[k]+elmt[k+1])/2 over interior nodes
            float s = ep * 0.5f * (el + el1);
#pragma unroll
            for (int off = 32; off; off >>= 1) s += __shfl_xor(s, off);
            const float scale = (1.0f - e0e63 * 5e-7f) / s;
            const float epu = __shfl_up(ep, 1);
            const float pdl = (lane == 0)  ? 1e-6f : scale * epu;  // pdf[lane]
            const float pdn = (lane == 63) ? 1e-6f : scale * ep;   // pdf[lane+1]
            const float cell = 0.5f * (pdl + pdn) * el;
            // inclusive scan -> exclusive prefix
            float v = cell;
#pragma unroll
            for (int off = 1; off < 64; off <<= 1) {
                float u = __shfl_up(v, off);
                if (lane >= off) v += u;
            }
            stbl[(d << 6) | lane] = make_float4(pdl, (pdn - pdl) / el, v - cell, m0);
        }
    }
    __syncthreads();

    // ---- per-half-point body: 4 dims, one shfl_xor to combine logdet ----
    auto body = [&](float4 X, float Lin, int g) {
        const int q     = g >> 1;
        const int dbase = (g & 1) << 2;            // dims 0-3 or 4-7
        float xd[4] = {X.x, X.y, X.z, X.w};
        float yd[4], dd4[4];
        float extra = 0.0f;

#pragma unroll
        for (int dl = 0; dl < 4; ++dl) {
            float xo = xd[dl];
            float xs = fmaf(xo, 0.05f, 0.5f);            // (x+10)/20 to 1 ulp
            // analytic bin: g = log2(1 + alpha*|x|)/log2(1.2); one v_log_f32
            float gg = __log2f(fmaf(ALPHA, fabsf(xo), 1.0f)) * INV_LOG2R;
            // merged index: CDF & derivative are continuous at bin boundaries,
            // so boundary misclassification (gg exactly integral) is harmless.
            int jf = (int)fminf(gg, 31.0f);
            int k  = (xo >= 0.0f) ? (32 + jf) : (31 - jf);

            float4 tb = stbl[((dbase + dl) << 6) + k];   // {v1, slope, F_pre, mesh_k}
            float xm  = xs - tb.w;
            bool cov  = (xs >= 0.0f) && (xs < 1.0f);

            float yc = tb.z + xm * fmaf(0.5f * xm, tb.y, tb.x);
            float dv = fmaf(xm, tb.y, tb.x);
            float yy = cov ? yc : xs;
            dd4[dl]  = cov ? dv : 1.0f;

            yy = fmaf(yy, 20.0f, -10.0f);
            if (yy > 10.0f)  { yy = fmaf(1e-6f, yy - 10.0f, 10.0f);  extra += LOG_BETA; }
            if (yy < -10.0f) { yy = fmaf(1e-6f, yy + 10.0f, -10.0f); extra += LOG_BETA; }
            yd[dl] = yy;
        }

        // 2 x v_log_f32 of pairwise products (each product >= 1e-12, no underflow)
        float l2 = __log2f(dd4[0] * dd4[1]) + __log2f(dd4[2] * dd4[3]);
        float contrib = fmaf(l2, LN2F, extra);
        float cross   = __shfl_xor(contrib, 1);    // partner half-point

        f32x4 yv = { yd[0], yd[1], yd[2], yd[3] };
        __builtin_nontemporal_store(yv, (f32x4*)y_out + g);
        if ((g & 1) == 0)
            __builtin_nontemporal_store(Lin + contrib + cross, ld_out + q);
    };

    // ---- main loop: guard-free 3-stage (2 loads in flight) software pipeline ----
    for (int j = 0; j < iters; ++j) {
        float4 Xn; float Ln;
        const bool more = (j + 2 < iters);         // wave-uniform
        if (more) {
            int gx = i0 + (j + 2) * T;
            Xn = xv4[gx];
            Ln = logdet_in[gx >> 1];
        }
        __builtin_amdgcn_sched_barrier(0);         // keep prefetch above the compute

        body(X0, L0, i0 + j * T);

        X0 = X1; L0 = L1;
        if (more) { X1 = Xn; L1 = Ln; }
    }

    // ---- remainder (never runs when T | G; kept for generality) ----
    int gr = i0 + iters * T;
    if (gr < G) {
        body(xv4[gr], logdet_in[gr >> 1], gr);     // pairs never split: G is even,
                                                   // partner is adjacent lane
    }
}

extern "C" void kernel_launch(void* const* d_in, const int* in_sizes, int n_in,
                              void* d_out, int out_size, void* d_ws, size_t ws_size,
                              hipStream_t stream) {
    const float* x      = (const float*)d_in[0];   // [N, 8]
    const float* logdet = (const float*)d_in[1];   // [N, 1]
    const float* p      = (const float*)d_in[2];   // [63, 8]

    const int n = in_sizes[1];                     // N points
    float* y_out  = (float*)d_out;                 // [N*8]
    float* ld_out = (float*)d_out + (size_t)n * NDIM;  // [N]

    const int block = 256;
    int grid = 2048;                               // 8 blocks/CU co-resident
    if ((long long)grid * block > 2LL * n) grid = (2 * n + block - 1) / block;
    cdfq_fused<<<grid, block, 0, stream>>>(x, logdet, p, y_out, ld_out, n);
}